// Round 9
// baseline (1762.274 us; speedup 1.0000x reference)
//
#include <hip/hip_runtime.h>
#include <math.h>

#define HIDDEN 512
#define INPUT  64
#define NB     64     // distinct batch rows (8 trials are bit-identical replicas)
#define NT     8
#define WARM   100
#define RESP   400
#define STEPS  (WARM + RESP)
#define ALPHA  0.1f

typedef _Float16 half8  __attribute__((ext_vector_type(8)));
typedef _Float16 half2v __attribute__((ext_vector_type(2)));

#if defined(__has_builtin)
#  if __has_builtin(__builtin_amdgcn_fdot2)
#    define HAS_FDOT2 1
#  endif
#endif

__device__ __forceinline__ void dot8(half8 w, half8 s, float& a0, float& a1) {
#ifdef HAS_FDOT2
  a0 = __builtin_amdgcn_fdot2(__builtin_shufflevector(w, w, 0, 1),
                              __builtin_shufflevector(s, s, 0, 1), a0, false);
  a1 = __builtin_amdgcn_fdot2(__builtin_shufflevector(w, w, 2, 3),
                              __builtin_shufflevector(s, s, 2, 3), a1, false);
  a0 = __builtin_amdgcn_fdot2(__builtin_shufflevector(w, w, 4, 5),
                              __builtin_shufflevector(s, s, 4, 5), a0, false);
  a1 = __builtin_amdgcn_fdot2(__builtin_shufflevector(w, w, 6, 7),
                              __builtin_shufflevector(s, s, 6, 7), a1, false);
#else
#pragma unroll
  for (int l = 0; l < 8; ++l)
    ((l & 1) ? a1 : a0) = fmaf((float)w[l], (float)s[l], (l & 1) ? a1 : a0);
#endif
}

// ---------------- workspace layout (bytes) ----------------
#define OFF_W    0                          // f16 Wstage, 512 KB
#define OFF_SPEX (512 * 1024)               // u32 sp_ex[NB][512] f32-bits, 128 KB
#define OFF_OSUM (OFF_SPEX + NB * HIDDEN * 4)  // u32 osum[NB][4]
#define OFF_FLAG (OFF_OSUM + 1024)             // u32 flags[NB][4]
#define WS_NEED  (OFF_FLAG + 1024)

// Stage W_rec fp32[j][k] -> f16 in EXACTLY the main kernel's load order:
// Wstage element for (q, c, t, l) at ((q*8+c)*1024 + t)*8 + l
//   <- W_rec[q*128 + (t>>3)][(t&7)*64 + c*8 + l]
__global__ void stage_quad_kernel(const float* __restrict__ W,
                                  _Float16* __restrict__ Wst) {
  const int gid = blockIdx.x * blockDim.x + threadIdx.x;  // 0..32767
  const int q  = gid >> 13;
  const int c  = (gid >> 10) & 7;
  const int tm = gid & 1023;
  const int jg = q * 128 + (tm >> 3);
  const int kb = (tm & 7) * 64 + c * 8;
  const float* src = W + (size_t)jg * HIDDEN + kb;
  _Float16* dst = Wst + ((size_t)(q * 8 + c) * 1024 + tm) * 8;
#pragma unroll
  for (int l = 0; l < 8; ++l) dst[l] = (_Float16)src[l];
}

// 256 wgs = 64 rows x 4 j-quarters; 1024 threads; W quarter (128KB) fully in
// LDS -> zero register-residency requirements (allocator-proof). Per-step
// cross-wg sp exchange via relaxed agent-scope atomics (PoC-coherent,
// placement-independent) + per-wg monotone flag.
__global__ void __launch_bounds__(1024)
leaky_rnn_quad_kernel(const float* __restrict__ inputs,
                      const float* __restrict__ W_in,
                      const float* __restrict__ b_in,
                      const _Float16* __restrict__ Wst,
                      const float* __restrict__ w_out,
                      const float* __restrict__ b_out,
                      unsigned* __restrict__ sp_ex,    // [NB][512] f32 bits
                      unsigned* __restrict__ osum_ex,  // [NB][4]
                      unsigned* __restrict__ flags,    // [NB][4]
                      float* __restrict__ out /*[NB][NT][RESP]*/) {
  const int wg = blockIdx.x;
  const int r = wg & 63;   // row
  const int q = wg >> 6;   // j-quarter; quad {r, r+64, r+128, r+192} same XCD (heuristic)
  const int t = threadIdx.x;
  const int jl = t >> 3;   // local j 0..127
  const int kq = t & 7;    // 64-wide k-eighth
  const int jg = q * 128 + jl;

  __shared__ __align__(16) _Float16 ldsW[8 * 1024 * 8];  // 128 KB
  // sp staging: ping-pong gens x 8 regions of 64 sp (+8 pad) -> region stride
  // 144B puts the 8 regions in disjoint bank quads (dword off 0,36,72,... %32
  // = 0,4,8,...,28) -> conflict-free per-kq broadcast reads.
  __shared__ __align__(16) _Float16 spst[2][8 * 72];
  __shared__ float xin[INPUT];
  __shared__ float wsum[16];

  half8* ldsW8 = (half8*)ldsW;
  const half8* Ws = (const half8*)Wst + (size_t)q * 8 * 1024;
#pragma unroll
  for (int c = 0; c < 8; ++c) ldsW8[c * 1024 + t] = Ws[c * 1024 + t];  // coalesced

  if (t < INPUT) xin[t] = inputs[r * INPUT + t];
  if (t < 8 * 72) spst[0][t] = (_Float16)0.6931471805599453f;  // softplus(0)
  __syncthreads();

  float ic = b_in[jg];
  const float* wi = W_in + (size_t)jg * INPUT;
#pragma unroll
  for (int i = 0; i < INPUT; ++i) ic = fmaf(xin[i], wi[i], ic);
  const float wout = w_out[jg];
  const float bout = b_out[0];
  float h = 0.f;

  unsigned* const spex_r = sp_ex + r * HIDDEN;
  unsigned* const osum_r = osum_ex + r * 4;
  unsigned* const flag_r = flags + r * 4;
  float* const ob = out + (size_t)r * (NT * RESP);

  for (int step = 0; step < STEPS; ++step) {
    const int p = step & 1;
    const _Float16* spg = &spst[p][kq * 72];

    float a0 = 0.f, a1 = 0.f;
#pragma unroll
    for (int c = 0; c < 8; ++c) {
      half8 w = ldsW8[c * 1024 + t];            // conflict-free, full BW
      half8 s = *(const half8*)(spg + c * 8);   // per-kq broadcast, staggered banks
      dot8(w, s, a0, a1);
    }
    float d = a0 + a1;
    d += __shfl_xor(d, 1);   // merge the 8 k-eighth partials (in-wave)
    d += __shfl_xor(d, 2);
    d += __shfl_xor(d, 4);

    h = h * (1.f - ALPHA) + ALPHA * (d + ic);
    const float spf = fmaxf(h, 0.f) + log1pf(expf(-fabsf(h)));  // stable softplus

    if (kq == 0) {
      spst[1 - p][(jg >> 6) * 72 + (jg & 63)] = (_Float16)spf;  // own slice, local
      __hip_atomic_store(&spex_r[jg], __builtin_bit_cast(unsigned, spf),
                         __ATOMIC_RELAXED, __HIP_MEMORY_SCOPE_AGENT);
    }
    if (step >= WARM) {
      float v = (kq == 0) ? h * wout : 0.f;
#pragma unroll
      for (int off = 32; off; off >>= 1) v += __shfl_down(v, off);
      if ((t & 63) == 0) wsum[t >> 6] = v;
    }
    __syncthreads();  // own staging + wsum visible; every wave's publishes drained

    if (t == 0) {
      if (step >= WARM) {
        float os = 0.f;
#pragma unroll
        for (int w = 0; w < 16; ++w) os += wsum[w];
        __hip_atomic_store(&osum_r[q], __builtin_bit_cast(unsigned, os),
                           __ATOMIC_RELAXED, __HIP_MEMORY_SCOPE_AGENT);
      }
      asm volatile("s_waitcnt vmcnt(0)" ::: "memory");  // osum ack'd at PoC
      __hip_atomic_store(&flag_r[q], (unsigned)(step + 1),
                         __ATOMIC_RELAXED, __HIP_MEMORY_SCOPE_AGENT);
    }
    if (t < 3) {  // 3 lanes spin one peer flag each
      const int pq = t + (t >= q ? 1 : 0);
      long guard = 0;
      while (__hip_atomic_load(&flag_r[pq], __ATOMIC_RELAXED,
                               __HIP_MEMORY_SCOPE_AGENT) <= (unsigned)step) {
        if (++guard > (1L << 27)) break;  // loud-failure bailout, never trips normally
      }
    }
    __syncthreads();  // peers' data now PoC-visible

    if (t < 384) {  // stage 3 peer slices (384 sp) into next-gen regions
      const int k = t + (t >= q * 128 ? 128 : 0);
      unsigned u = __hip_atomic_load(&spex_r[k], __ATOMIC_RELAXED,
                                     __HIP_MEMORY_SCOPE_AGENT);
      spst[1 - p][(k >> 6) * 72 + (k & 63)] =
          (_Float16)__builtin_bit_cast(float, u);
    }
    if (step >= WARM && q == 0 && t == 0) {
      float o = bout;
#pragma unroll
      for (int qq = 0; qq < 4; ++qq)
        o += __builtin_bit_cast(
            float, __hip_atomic_load(&osum_r[qq], __ATOMIC_RELAXED,
                                     __HIP_MEMORY_SCOPE_AGENT));
      const float hz = 1.f / (1.f + expf(-o));
#pragma unroll
      for (int tr = 0; tr < NT; ++tr) ob[tr * RESP + (step - WARM)] = hz;
    }
    __syncthreads();  // next-gen staging complete
  }
}

// ============== fallback 1: R4 single-wg kernel (ws >= 512KB) ==============
__device__ __forceinline__ void dot8f(float w0, float w1, float w2, float w3,
                                      half8 s, float& a0, float& a1) {
#ifdef HAS_FDOT2
  a0 = __builtin_amdgcn_fdot2(__builtin_bit_cast(half2v, w0),
                              __builtin_shufflevector(s, s, 0, 1), a0, false);
  a1 = __builtin_amdgcn_fdot2(__builtin_bit_cast(half2v, w1),
                              __builtin_shufflevector(s, s, 2, 3), a1, false);
  a0 = __builtin_amdgcn_fdot2(__builtin_bit_cast(half2v, w2),
                              __builtin_shufflevector(s, s, 4, 5), a0, false);
  a1 = __builtin_amdgcn_fdot2(__builtin_bit_cast(half2v, w3),
                              __builtin_shufflevector(s, s, 6, 7), a1, false);
#else
  const float wf[4] = {w0, w1, w2, w3};
#pragma unroll
  for (int pp = 0; pp < 4; ++pp) {
    half2v wp = __builtin_bit_cast(half2v, wf[pp]);
    float& a = (pp & 1) ? a1 : a0;
    a = fmaf((float)wp[0], (float)s[2 * pp], a);
    a = fmaf((float)wp[1], (float)s[2 * pp + 1], a);
  }
#endif
}

#define NREGC 23
#define NLDSC 9

__global__ void convert_w_pack_kernel(const float* __restrict__ W,
                                      _Float16* __restrict__ Wpk) {
  const int t = blockIdx.x * blockDim.x + threadIdx.x;
  const int kblk = t & 63;
  const int j = t >> 6;
  const float* src = W + (size_t)j * HIDDEN + kblk * 8;
  _Float16* dst = Wpk + ((size_t)kblk * HIDDEN + j) * 8;
#pragma unroll
  for (int l = 0; l < 8; ++l) dst[l] = (_Float16)src[l];
}

__global__ void __launch_bounds__(1024)
leaky_rnn_res_kernel(const float* __restrict__ inputs,
                     const float* __restrict__ W_in,
                     const float* __restrict__ b_in,
                     const _Float16* __restrict__ Wpk,
                     const float* __restrict__ w_out,
                     const float* __restrict__ b_out,
                     float* __restrict__ out) {
  const int b = blockIdx.x;
  const int t = threadIdx.x;
  const int j = t & (HIDDEN - 1);
  const int kh = t >> 9;

  __shared__ __align__(16) half8 ldsW[NLDSC][1024];
  __shared__ __align__(16) _Float16 sp_h[HIDDEN];
  __shared__ float xin[INPUT];
  __shared__ float redk[HIDDEN];
  __shared__ float wsum[8];

  const half8* __restrict__ Wp8 =
      (const half8*)Wpk + (size_t)(kh * 32) * HIDDEN + j;
  const float4* __restrict__ Wp4 = (const float4*)Wp8;

  float wrf[NREGC * 4];
#pragma unroll
  for (int c = 0; c < NREGC; ++c) {
    float4 v = Wp4[(size_t)c * HIDDEN];
    wrf[4 * c + 0] = v.x; wrf[4 * c + 1] = v.y;
    wrf[4 * c + 2] = v.z; wrf[4 * c + 3] = v.w;
    asm volatile("" : "+v"(wrf[4 * c + 0]), "+v"(wrf[4 * c + 1]),
                      "+v"(wrf[4 * c + 2]), "+v"(wrf[4 * c + 3]));
  }
#pragma unroll
  for (int c = 0; c < NLDSC; ++c) ldsW[c][t] = Wp8[(size_t)(NREGC + c) * HIDDEN];

  if (t < INPUT) xin[t] = inputs[b * INPUT + t];
  __syncthreads();

  float ic = 0.f, wout = 0.f;
  const float bout = b_out[0];
  if (t < HIDDEN) {
    ic = b_in[j];
    const float* wi = W_in + (size_t)j * INPUT;
#pragma unroll
    for (int i = 0; i < INPUT; ++i) ic = fmaf(xin[i], wi[i], ic);
    wout = w_out[j];
    sp_h[j] = (_Float16)0.6931471805599453f;
  }
  float h = 0.f;
  __syncthreads();

  const half8* sp8 = ((const half8*)sp_h) + kh * 32;
  float* const ob = out + (size_t)b * (NT * RESP) + (t < NT ? t * RESP : 0);

  for (int step = 0; step < STEPS; ++step) {
    float a0 = 0.f, a1 = 0.f;
#pragma unroll
    for (int c = 0; c < NLDSC; ++c) dot8(ldsW[c][t], sp8[NREGC + c], a0, a1);
#pragma unroll
    for (int c = 0; c < NREGC; ++c)
      dot8f(wrf[4 * c + 0], wrf[4 * c + 1], wrf[4 * c + 2], wrf[4 * c + 3],
            sp8[c], a0, a1);
    const float acc = a0 + a1;

    if (t >= HIDDEN) redk[j] = acc;
    __syncthreads();

    if (t < HIDDEN) {
      const float rec = acc + redk[j];
      h = h * (1.f - ALPHA) + ALPHA * (rec + ic);
      sp_h[j] = (_Float16)(fmaxf(h, 0.f) + log1pf(expf(-fabsf(h))));
      if (step >= WARM) {
        float v = h * wout;
#pragma unroll
        for (int off = 32; off > 0; off >>= 1) v += __shfl_down(v, off);
        if ((t & 63) == 0) wsum[t >> 6] = v;
      }
    }
    __syncthreads();

    if (step >= WARM && t < NT) {
      float o = bout;
#pragma unroll
      for (int w = 0; w < 8; ++w) o += wsum[w];
      ob[step - WARM] = 1.f / (1.f + expf(-o));
    }
  }
}

// ============== fallback 2: fp32 row kernel (tiny ws) ==============
__global__ void __launch_bounds__(512, 1)
leaky_rnn_row_kernel(const float* __restrict__ inputs,
                     const float* __restrict__ W_in,
                     const float* __restrict__ b_in,
                     const float* __restrict__ W_rec,
                     const float* __restrict__ w_out,
                     const float* __restrict__ b_out,
                     float* __restrict__ out) {
  const int b = blockIdx.x;
  const int j = threadIdx.x;
  __shared__ float sp[HIDDEN];
  __shared__ float xin[INPUT];
  __shared__ float red[8];
  if (j < INPUT) xin[j] = inputs[b * INPUT + j];
  __syncthreads();
  float ic = b_in[j];
  const float* wi = W_in + j * INPUT;
#pragma unroll
  for (int i = 0; i < INPUT; ++i) ic = fmaf(xin[i], wi[i], ic);
  const float wout = w_out[j];
  const float bout = b_out[0];
  float h = 0.0f;
  sp[j] = 0.6931471805599453f;
  __syncthreads();
  const float4* __restrict__ Wr = (const float4*)(W_rec + (size_t)j * HIDDEN);
  for (int step = 0; step < STEPS; ++step) {
    float rec = 0.0f;
#pragma unroll 8
    for (int k4 = 0; k4 < HIDDEN / 4; ++k4) {
      float4 w = Wr[k4];
      float4 s = *(const float4*)&sp[4 * k4];
      rec = fmaf(w.x, s.x, rec); rec = fmaf(w.y, s.y, rec);
      rec = fmaf(w.z, s.z, rec); rec = fmaf(w.w, s.w, rec);
    }
    h = h * (1.0f - ALPHA) + ALPHA * (rec + ic);
    if (step >= WARM) {
      float v = h * wout;
#pragma unroll
      for (int off = 32; off > 0; off >>= 1) v += __shfl_down(v, off);
      if ((j & 63) == 0) red[j >> 6] = v;
    }
    __syncthreads();
    sp[j] = fmaxf(h, 0.0f) + log1pf(expf(-fabsf(h)));
    if (step >= WARM && j == 0) {
      float o = bout;
#pragma unroll
      for (int w = 0; w < 8; ++w) o += red[w];
      const float hz = 1.0f / (1.0f + expf(-o));
      float* obp = out + (size_t)b * (NT * RESP) + (step - WARM);
#pragma unroll
      for (int tr = 0; tr < NT; ++tr) obp[tr * RESP] = hz;
    }
    __syncthreads();
  }
}

extern "C" void kernel_launch(void* const* d_in, const int* in_sizes, int n_in,
                              void* d_out, int out_size, void* d_ws, size_t ws_size,
                              hipStream_t stream) {
  const float* inputs = (const float*)d_in[0];
  const float* W_in   = (const float*)d_in[1];
  const float* b_in   = (const float*)d_in[2];
  const float* W_rec  = (const float*)d_in[3];
  const float* w_out  = (const float*)d_in[4];
  const float* b_out  = (const float*)d_in[5];
  float* out = (float*)d_out;

  if (ws_size >= (size_t)WS_NEED) {
    char* ws = (char*)d_ws;
    _Float16* Wst  = (_Float16*)(ws + OFF_W);
    unsigned* spex = (unsigned*)(ws + OFF_SPEX);
    unsigned* osum = (unsigned*)(ws + OFF_OSUM);
    unsigned* flg  = (unsigned*)(ws + OFF_FLAG);
    hipMemsetAsync(flg, 0, NB * 4 * sizeof(unsigned), stream);  // reset every launch
    stage_quad_kernel<<<dim3(128), dim3(256), 0, stream>>>(W_rec, Wst);
    leaky_rnn_quad_kernel<<<dim3(256), dim3(1024), 0, stream>>>(
        inputs, W_in, b_in, Wst, w_out, b_out, spex, osum, flg, out);
  } else if (ws_size >= (size_t)HIDDEN * HIDDEN * sizeof(_Float16)) {
    _Float16* Wpk = (_Float16*)d_ws;
    convert_w_pack_kernel<<<dim3(HIDDEN * 64 / 256), dim3(256), 0, stream>>>(W_rec, Wpk);
    leaky_rnn_res_kernel<<<dim3(NB), dim3(2 * HIDDEN), 0, stream>>>(
        inputs, W_in, b_in, Wpk, w_out, b_out, out);
  } else {
    leaky_rnn_row_kernel<<<dim3(NB), dim3(HIDDEN), 0, stream>>>(
        inputs, W_in, b_in, W_rec, w_out, b_out, out);
  }
}

// Round 10
// 1294.906 us; speedup vs baseline: 1.3609x; 1.3609x over previous
//
#include <hip/hip_runtime.h>
#include <math.h>

#define HIDDEN 512
#define INPUT  64
#define NB     64     // distinct batch rows (8 trials are bit-identical replicas)
#define NT     8
#define WARM   100
#define RESP   400
#define STEPS  (WARM + RESP)
#define ALPHA  0.1f

// 32 half8 chunks per thread (one k-half of one row): split
#define NAGPC  16     // chunks 0..15  pinned in AGPRs (64 AGPRs, unified file)
#define NSTRC  7      // chunks 16..22 streamed from L2 each step (112 KB/CU)
#define NLDSC  9      // chunks 23..31 in LDS (144 KB) — identical to R4 layout

typedef _Float16 half8  __attribute__((ext_vector_type(8)));
typedef _Float16 half2v __attribute__((ext_vector_type(2)));

#if defined(__has_builtin)
#  if __has_builtin(__builtin_amdgcn_fdot2)
#    define HAS_FDOT2 1
#  endif
#endif

__device__ __forceinline__ void dot8(half8 w, half8 s, float& a0, float& a1) {
#ifdef HAS_FDOT2
  a0 = __builtin_amdgcn_fdot2(__builtin_shufflevector(w, w, 0, 1),
                              __builtin_shufflevector(s, s, 0, 1), a0, false);
  a1 = __builtin_amdgcn_fdot2(__builtin_shufflevector(w, w, 2, 3),
                              __builtin_shufflevector(s, s, 2, 3), a1, false);
  a0 = __builtin_amdgcn_fdot2(__builtin_shufflevector(w, w, 4, 5),
                              __builtin_shufflevector(s, s, 4, 5), a0, false);
  a1 = __builtin_amdgcn_fdot2(__builtin_shufflevector(w, w, 6, 7),
                              __builtin_shufflevector(s, s, 6, 7), a1, false);
#else
#pragma unroll
  for (int l = 0; l < 8; ++l)
    ((l & 1) ? a1 : a0) = fmaf((float)w[l], (float)s[l], (l & 1) ? a1 : a0);
#endif
}

// w chunk supplied as 4 floats (each = 2 packed f16)
__device__ __forceinline__ void dot8f(float w0, float w1, float w2, float w3,
                                      half8 s, float& a0, float& a1) {
#ifdef HAS_FDOT2
  a0 = __builtin_amdgcn_fdot2(__builtin_bit_cast(half2v, w0),
                              __builtin_shufflevector(s, s, 0, 1), a0, false);
  a1 = __builtin_amdgcn_fdot2(__builtin_bit_cast(half2v, w1),
                              __builtin_shufflevector(s, s, 2, 3), a1, false);
  a0 = __builtin_amdgcn_fdot2(__builtin_bit_cast(half2v, w2),
                              __builtin_shufflevector(s, s, 4, 5), a0, false);
  a1 = __builtin_amdgcn_fdot2(__builtin_bit_cast(half2v, w3),
                              __builtin_shufflevector(s, s, 6, 7), a1, false);
#else
  const float wf[4] = {w0, w1, w2, w3};
#pragma unroll
  for (int p = 0; p < 4; ++p) {
    half2v wp = __builtin_bit_cast(half2v, wf[p]);
    float& a = (p & 1) ? a1 : a0;
    a = fmaf((float)wp[0], (float)s[2 * p], a);
    a = fmaf((float)wp[1], (float)s[2 * p + 1], a);
  }
#endif
}

// AGPR pin/unpin (gfx950 unified VGPR/AGPR file; AGPRs are OUTSIDE the
// compiler's 64-VGPR default budget -> 64 extra registers per thread).
__device__ __forceinline__ void ag_write(float& a, float v) {
  asm volatile("v_accvgpr_write_b32 %0, %1" : "=a"(a) : "v"(v));
}
__device__ __forceinline__ float ag_read(const float& a) {
  float v;
  asm volatile("v_accvgpr_read_b32 %0, %1" : "=v"(v) : "a"(a));
  return v;
}

// Pack W_rec fp32 [j][k] -> f16 Wpk[k>>3][j][8] (coalesced main-kernel loads).
__global__ void convert_w_pack_kernel(const float* __restrict__ W,
                                      _Float16* __restrict__ Wpk) {
  const int t = blockIdx.x * blockDim.x + threadIdx.x;  // HIDDEN*64 threads
  const int kblk = t & 63;
  const int j = t >> 6;
  const float* src = W + (size_t)j * HIDDEN + kblk * 8;
  _Float16* dst = Wpk + ((size_t)kblk * HIDDEN + j) * 8;
#pragma unroll
  for (int l = 0; l < 8; ++l) dst[l] = (_Float16)src[l];
}

// One wg per distinct batch row; 1024 threads = 2 k-halves x 512 j.
// W residency: 9 chunks LDS + 16 chunks AGPR + 7 chunks L2-streamed.
// VGPR(<=64) + AGPR(64) = 128/wave = the HW limit at 4 waves/SIMD (1 wg/CU,
// forced by 151KB LDS) -> launchable, and no scratch spill.
__global__ void __launch_bounds__(1024)
leaky_rnn_ag_kernel(const float* __restrict__ inputs,
                    const float* __restrict__ W_in,
                    const float* __restrict__ b_in,
                    const _Float16* __restrict__ Wpk,
                    const float* __restrict__ w_out,
                    const float* __restrict__ b_out,
                    float* __restrict__ out /*[NB][NT][RESP]*/) {
  const int b = blockIdx.x;
  const int t = threadIdx.x;
  const int j = t & (HIDDEN - 1);
  const int kh = t >> 9;  // 0 or 1

  __shared__ __align__(16) half8 ldsW[NLDSC][1024];   // 144 KB, chunk-major
  __shared__ __align__(16) _Float16 sp_h[HIDDEN];     // softplus(h) as f16
  __shared__ float xin[INPUT];
  __shared__ float redk[HIDDEN];  // upper-k-half partial dots
  __shared__ float wsum[8];       // per-wave w_out.h partials

  const half8* __restrict__ Wp8 =
      (const half8*)Wpk + (size_t)(kh * 32) * HIDDEN + j;
  const float4* __restrict__ Wp4 = (const float4*)Wp8;  // same addresses

  // ---- init: chunks 0..15 -> AGPRs; 23..31 -> LDS ----
  float ag[NAGPC * 4];  // values live in AGPR class (all def/use sites are "a")
#pragma unroll
  for (int c = 0; c < NAGPC; ++c) {
    float4 v = Wp4[(size_t)c * HIDDEN];
    ag_write(ag[4 * c + 0], v.x);
    ag_write(ag[4 * c + 1], v.y);
    ag_write(ag[4 * c + 2], v.z);
    ag_write(ag[4 * c + 3], v.w);
  }
#pragma unroll
  for (int c = 0; c < NLDSC; ++c)
    ldsW[c][t] = Wp8[(size_t)(NAGPC + NSTRC + c) * HIDDEN];

  if (t < INPUT) xin[t] = inputs[b * INPUT + t];
  __syncthreads();  // xin + ldsW visible

  float ic = 0.f, wout = 0.f;
  const float bout = b_out[0];
  if (t < HIDDEN) {
    ic = b_in[j];
    const float* wi = W_in + (size_t)j * INPUT;
#pragma unroll
    for (int i = 0; i < INPUT; ++i) ic = fmaf(xin[i], wi[i], ic);
    wout = w_out[j];
    sp_h[j] = (_Float16)0.6931471805599453f;  // softplus(0)
  }
  float h = 0.f;
  __syncthreads();  // sp_h visible

  const half8* sp8 = ((const half8*)sp_h) + kh * 32;
  float* const ob = out + (size_t)b * (NT * RESP) + (t < NT ? t * RESP : 0);

  for (int step = 0; step < STEPS; ++step) {
    // issue the 7 streamed-chunk loads up front; they fly under the dots
    float4 st0 = Wp4[(size_t)(NAGPC + 0) * HIDDEN];
    float4 st1 = Wp4[(size_t)(NAGPC + 1) * HIDDEN];
    float4 st2 = Wp4[(size_t)(NAGPC + 2) * HIDDEN];
    float4 st3 = Wp4[(size_t)(NAGPC + 3) * HIDDEN];
    float4 st4 = Wp4[(size_t)(NAGPC + 4) * HIDDEN];
    float4 st5 = Wp4[(size_t)(NAGPC + 5) * HIDDEN];
    float4 st6 = Wp4[(size_t)(NAGPC + 6) * HIDDEN];

    float a0 = 0.f, a1 = 0.f;
    // LDS-resident chunks (ds reads overlap the global loads)
#pragma unroll
    for (int c = 0; c < NLDSC; ++c)
      dot8(ldsW[c][t], sp8[NAGPC + NSTRC + c], a0, a1);
    // AGPR-resident chunks (pure register traffic)
#pragma unroll
    for (int c = 0; c < NAGPC; ++c) {
      float w0 = ag_read(ag[4 * c + 0]);
      float w1 = ag_read(ag[4 * c + 1]);
      float w2 = ag_read(ag[4 * c + 2]);
      float w3 = ag_read(ag[4 * c + 3]);
      dot8f(w0, w1, w2, w3, sp8[c], a0, a1);
    }
    // streamed chunks (data has landed by now)
    dot8f(st0.x, st0.y, st0.z, st0.w, sp8[NAGPC + 0], a0, a1);
    dot8f(st1.x, st1.y, st1.z, st1.w, sp8[NAGPC + 1], a0, a1);
    dot8f(st2.x, st2.y, st2.z, st2.w, sp8[NAGPC + 2], a0, a1);
    dot8f(st3.x, st3.y, st3.z, st3.w, sp8[NAGPC + 3], a0, a1);
    dot8f(st4.x, st4.y, st4.z, st4.w, sp8[NAGPC + 4], a0, a1);
    dot8f(st5.x, st5.y, st5.z, st5.w, sp8[NAGPC + 5], a0, a1);
    dot8f(st6.x, st6.y, st6.z, st6.w, sp8[NAGPC + 6], a0, a1);
    const float acc = a0 + a1;

    if (t >= HIDDEN) redk[j] = acc;  // upper k-half publishes partial
    __syncthreads();                 // redk ready; sp_h reads complete

    if (t < HIDDEN) {
      const float rec = acc + redk[j];
      h = h * (1.f - ALPHA) + ALPHA * (rec + ic);
      const float sp = fmaxf(h, 0.f) + log1pf(expf(-fabsf(h)));  // stable softplus
      sp_h[j] = (_Float16)sp;
      if (step >= WARM) {
        float v = h * wout;
#pragma unroll
        for (int off = 32; off > 0; off >>= 1) v += __shfl_down(v, off);
        if ((t & 63) == 0) wsum[t >> 6] = v;
      }
    }
    __syncthreads();  // new sp_h + wsum visible

    if (step >= WARM && t < NT) {
      float o = bout;
#pragma unroll
      for (int w = 0; w < 8; ++w) o += wsum[w];
      const float hz = 1.f / (1.f + expf(-o));
      ob[step - WARM] = hz;  // 8 identical trial copies, one lane each
    }
  }
}

// ---------------- fp32 fallback (round-0 kernel) for tiny ws ----------------
__global__ void __launch_bounds__(512, 1)
leaky_rnn_row_kernel(const float* __restrict__ inputs,
                     const float* __restrict__ W_in,
                     const float* __restrict__ b_in,
                     const float* __restrict__ W_rec,
                     const float* __restrict__ w_out,
                     const float* __restrict__ b_out,
                     float* __restrict__ out) {
  const int b = blockIdx.x;
  const int j = threadIdx.x;
  __shared__ float sp[HIDDEN];
  __shared__ float xin[INPUT];
  __shared__ float red[8];
  if (j < INPUT) xin[j] = inputs[b * INPUT + j];
  __syncthreads();
  float ic = b_in[j];
  const float* wi = W_in + j * INPUT;
#pragma unroll
  for (int i = 0; i < INPUT; ++i) ic = fmaf(xin[i], wi[i], ic);
  const float wout = w_out[j];
  const float bout = b_out[0];
  float h = 0.0f;
  sp[j] = 0.6931471805599453f;
  __syncthreads();
  const float4* __restrict__ Wr = (const float4*)(W_rec + (size_t)j * HIDDEN);
  for (int step = 0; step < STEPS; ++step) {
    float rec = 0.0f;
#pragma unroll 8
    for (int k4 = 0; k4 < HIDDEN / 4; ++k4) {
      float4 w = Wr[k4];
      float4 s = *(const float4*)&sp[4 * k4];
      rec = fmaf(w.x, s.x, rec); rec = fmaf(w.y, s.y, rec);
      rec = fmaf(w.z, s.z, rec); rec = fmaf(w.w, s.w, rec);
    }
    h = h * (1.0f - ALPHA) + ALPHA * (rec + ic);
    if (step >= WARM) {
      float v = h * wout;
#pragma unroll
      for (int off = 32; off > 0; off >>= 1) v += __shfl_down(v, off);
      if ((j & 63) == 0) red[j >> 6] = v;
    }
    __syncthreads();
    sp[j] = fmaxf(h, 0.0f) + log1pf(expf(-fabsf(h)));
    if (step >= WARM && j == 0) {
      float o = bout;
#pragma unroll
      for (int w = 0; w < 8; ++w) o += red[w];
      const float hz = 1.0f / (1.0f + expf(-o));
      float* obp = out + (size_t)b * (NT * RESP) + (step - WARM);
#pragma unroll
      for (int tr = 0; tr < NT; ++tr) obp[tr * RESP] = hz;
    }
    __syncthreads();
  }
}

extern "C" void kernel_launch(void* const* d_in, const int* in_sizes, int n_in,
                              void* d_out, int out_size, void* d_ws, size_t ws_size,
                              hipStream_t stream) {
  const float* inputs = (const float*)d_in[0];
  const float* W_in   = (const float*)d_in[1];
  const float* b_in   = (const float*)d_in[2];
  const float* W_rec  = (const float*)d_in[3];
  const float* w_out  = (const float*)d_in[4];
  const float* b_out  = (const float*)d_in[5];
  float* out = (float*)d_out;

  const int nW = HIDDEN * HIDDEN;
  if (ws_size >= (size_t)nW * sizeof(_Float16)) {
    _Float16* Wpk = (_Float16*)d_ws;
    convert_w_pack_kernel<<<dim3(HIDDEN * 64 / 256), dim3(256), 0, stream>>>(W_rec, Wpk);
    leaky_rnn_ag_kernel<<<dim3(NB), dim3(2 * HIDDEN), 0, stream>>>(
        inputs, W_in, b_in, Wpk, w_out, b_out, out);
  } else {
    leaky_rnn_row_kernel<<<dim3(NB), dim3(HIDDEN), 0, stream>>>(
        inputs, W_in, b_in, W_rec, w_out, b_out, out);
  }
}